// Round 1
// 633.234 us; speedup vs baseline: 1.0338x; 1.0338x over previous
//
#include <hip/hip_runtime.h>

// FMoELinearProj — R3: both GEMMs rewritten as 256x256x(BK=64) 8-phase kernels
// (T2 granule-XOR swizzle + T3/T4 counted vmcnt(6) + T5 setprio, raw s_barrier
// so no compiler vmcnt(0) drain). GEMM2 split-K=4 + reduce4. cvt passes kept.
// Fallback to R1 path if ws_size < 272 MiB.

#define NEXP 16
#define TTOK 8192
#define DIN  1024
#define DOUT 4096
#define SDIM 512
#define LDSS 40   // fallback-path LDS stride

typedef short short8 __attribute__((ext_vector_type(8)));
typedef float floatx4 __attribute__((ext_vector_type(4)));
typedef unsigned short ushort_t;

__device__ __forceinline__ ushort_t f2bf(float f) {
    union { float f; unsigned u; } v; v.f = f;
    unsigned r = v.u + 0x7FFFu + ((v.u >> 16) & 1u);   // RNE
    return (ushort_t)(r >> 16);
}

#define GLL16(g, l) __builtin_amdgcn_global_load_lds( \
    (const __attribute__((address_space(1))) void*)(g), \
    (__attribute__((address_space(3))) void*)(l), 16, 0, 0)

// ---------------- fp32 -> bf16 streaming convert ----------------
__global__ __launch_bounds__(256)
void cvt_kernel(const float* __restrict__ src, ushort_t* __restrict__ dst, int n8) {
    const int i = blockIdx.x * 256 + threadIdx.x;
    if (i >= n8) return;
    const float4 a = ((const float4*)src)[2 * i];
    const float4 b = ((const float4*)src)[2 * i + 1];
    short8 o;
    o[0] = (short)f2bf(a.x); o[1] = (short)f2bf(a.y);
    o[2] = (short)f2bf(a.z); o[3] = (short)f2bf(a.w);
    o[4] = (short)f2bf(b.x); o[5] = (short)f2bf(b.y);
    o[6] = (short)f2bf(b.z); o[7] = (short)f2bf(b.w);
    ((short8*)dst)[i] = o;
}

// ============== 8-phase 256x256 GEMM, BK=64, bf16 (T2+T3+T4+T5) ==============
// A: [rows x LDK] bf16 (token-major), B: [cols x LDK] bf16 (row = output col).
// 8 waves = 2(M) x 4(N); per-wave output 128x64; acc[8][4] 16x16 frags.
// LDS: A/B each 2 bufs x 256rows x 64cols bf16 (64 KiB each, 128 KiB total).
// Buffer parity fixed: even K-tile -> buf 0, odd -> buf elem-offset 16384.
// Staging unit = quarter (64 rows x 64 cols = 8 KiB = one GLL16 of 512 thr).
// Granule swizzle: physical 16B-granule p holds logical g = p ^ (row&7),
// applied at the global source (gload_lds writes linearly) and on ds_read.
// Phase p computes M-frags {2p-2,2p-1} x all N x ksub{0,1} = 16 MFMA; B-frags
// for the K-tile are read once in phase 1/5 and held (8 x b128 = 32 VGPR).
// Stage schedule (iter i computes tiles 2i/2i+1, stages 2i+2/2i+3):
//  P1: buf1.Aq1,Aq3(t=2i+1)  P2: buf0.B0,B1   P3: buf0.B2,Aq0  P4: buf0.B3,Aq2 +vmcnt(6)
//  P5: buf0.Aq1,Aq3          P6: buf1.B0,B1   P7: buf1.B2,Aq0  P8: buf1.B3,Aq2 +vmcnt(6)
// Every staged region is dead (all cross-wave reads retired via the second
// barrier of the prior phase) before its stage issues; vmcnt(6)+barrier at
// phases 4/8 guarantees landing before first read. Never vmcnt(0) in loop.
template<bool G1>
__global__ __launch_bounds__(512, 2)
void gemm8p(const ushort_t* __restrict__ Ain, const int* __restrict__ counts,
            const ushort_t* __restrict__ Bin, const float* __restrict__ bias,
            ushort_t* __restrict__ Yout, float* __restrict__ Pout) {
    __shared__ __align__(16) ushort_t As[2 * 16384];
    __shared__ __align__(16) ushort_t Bs[2 * 16384];

    int e, mt, nt, kq;
    if constexpr (G1) {
        // 512 blocks -> 8 XCDs x 64 slots (2 experts/XCD); m fastest (W-tile share)
        const int l = ((blockIdx.x & 7) << 6) | (blockIdx.x >> 3);
        e = l >> 5; nt = (l >> 1) & 15; mt = l & 1; kq = 0;
    } else {
        // 256 blocks -> 8 XCDs x 32 slots (2 experts/XCD); m fastest
        const int l = ((blockIdx.x & 7) << 5) | (blockIdx.x >> 3);
        e = l >> 4; kq = (l >> 2) & 3; nt = (l >> 1) & 1; mt = l & 1;
    }
    const int LDK = G1 ? DIN : DOUT;

    int off = 0;
    for (int i = 0; i < e; ++i) off += counts[i];
    const int cnt = counts[e];

    const int tid = threadIdx.x, wave = tid >> 6, lane = tid & 63;
    const int wm = wave >> 2, wn = wave & 3;
    const int l15 = lane & 15, quad = lane >> 4;

    // staging geometry: wave covers 8 rows (1 KiB) of each 64-row quarter
    const int srow  = (wave << 3) + (lane >> 3);                       // row in quarter
    const int kbase = (G1 ? 0 : (kq << 10)) + (((lane & 7) ^ (lane >> 3)) << 3);

    const ushort_t* Bseg;
    if constexpr (G1) Bseg = Bin + (size_t)e * DOUT * DIN  + ((size_t)(nt << 8)) * DIN;
    else              Bseg = Bin + (size_t)e * SDIM * DOUT + ((size_t)(nt << 8)) * DOUT;
    const int aseg = off + (mt << 8);

    auto stA = [&](int bufe, int q, int kt) {
        int r = aseg + (q << 6) + srow; if (r >= TTOK) r = TTOK - 1;
        GLL16(Ain + (size_t)r * LDK + kbase + (kt << 6),
              As + bufe + (q << 12) + (wave << 9));
    };
    auto stB = [&](int bufe, int q, int kt) {
        GLL16(Bseg + (size_t)((q << 6) + srow) * LDK + kbase + (kt << 6),
              Bs + bufe + (q << 12) + (wave << 9));
    };
    auto rdA = [&](int bufe, int m, int s) -> short8 {
        return *(const short8*)&As[bufe + ((wm << 7) + (m << 4) + l15) * 64
                                   + ((((s << 2) | quad) ^ (lane & 7)) << 3)];
    };
    auto rdB = [&](int bufe, int n, int s) -> short8 {
        return *(const short8*)&Bs[bufe + ((wn << 6) + (n << 4) + l15) * 64
                                   + ((((s << 2) | quad) ^ (lane & 7)) << 3)];
    };

    floatx4 acc[8][4] = {};
    short8 bf[4][2], af0[2], af1[2];

#define RDB_ALL(BUFE) { _Pragma("unroll") \
    for (int n = 0; n < 4; ++n) { bf[n][0] = rdB(BUFE,n,0); bf[n][1] = rdB(BUFE,n,1); } }
#define RDA2(BUFE, M0) { af0[0]=rdA(BUFE,M0,0); af0[1]=rdA(BUFE,M0,1); \
                         af1[0]=rdA(BUFE,(M0)+1,0); af1[1]=rdA(BUFE,(M0)+1,1); }
#define MFMA16(M0) { \
    __builtin_amdgcn_s_setprio(1); \
    _Pragma("unroll") for (int n = 0; n < 4; ++n) { \
      acc[M0][n]     = __builtin_amdgcn_mfma_f32_16x16x32_bf16(af0[0], bf[n][0], acc[M0][n],     0,0,0); \
      acc[M0][n]     = __builtin_amdgcn_mfma_f32_16x16x32_bf16(af0[1], bf[n][1], acc[M0][n],     0,0,0); \
      acc[(M0)+1][n] = __builtin_amdgcn_mfma_f32_16x16x32_bf16(af1[0], bf[n][0], acc[(M0)+1][n], 0,0,0); \
      acc[(M0)+1][n] = __builtin_amdgcn_mfma_f32_16x16x32_bf16(af1[1], bf[n][1], acc[(M0)+1][n], 0,0,0); } \
    __builtin_amdgcn_s_setprio(0); }
#define BAR() __builtin_amdgcn_s_barrier()
#define VMC6() asm volatile("s_waitcnt vmcnt(6)" ::: "memory")

    // ---- prologue: buf0 <- tile0 (8 quarters); buf1 <- tile1 {B0..3,Aq0,Aq2}
    stA(0,0,0); stA(0,1,0); stA(0,2,0); stA(0,3,0);
    stB(0,0,0); stB(0,1,0); stB(0,2,0); stB(0,3,0);
    stB(16384,0,1); stB(16384,1,1); stB(16384,2,1); stB(16384,3,1);
    stA(16384,0,1); stA(16384,2,1);
    VMC6();                      // drain buf0's 8; keep buf1's 6 in flight
    BAR();

    #pragma unroll 1
    for (int it = 0; it < 8; ++it) {
        const int tn = 2 * it + 1;
        const int t2 = (it < 7) ? 2 * it + 2 : 0;   // clamped: keeps vmcnt counts uniform
        const int t3 = (it < 7) ? 2 * it + 3 : 1;

        // ======== K-tile even (buf0) ========
        RDB_ALL(0); RDA2(0, 0);
        stA(16384,1,tn); stA(16384,3,tn);
        BAR(); MFMA16(0); BAR();                    // phase 1

        RDA2(0, 2);
        stB(0,0,t2); stB(0,1,t2);
        BAR(); MFMA16(2); BAR();                    // phase 2

        RDA2(0, 4);
        stB(0,2,t2); stA(0,0,t2);
        BAR(); MFMA16(4); BAR();                    // phase 3

        RDA2(0, 6);
        stB(0,3,t2); stA(0,2,t2);
        VMC6();
        BAR(); MFMA16(6); BAR();                    // phase 4

        // ======== K-tile odd (buf1) ========
        RDB_ALL(16384); RDA2(16384, 0);
        stA(0,1,t2); stA(0,3,t2);
        BAR(); MFMA16(0); BAR();                    // phase 5

        RDA2(16384, 2);
        stB(16384,0,t3); stB(16384,1,t3);
        BAR(); MFMA16(2); BAR();                    // phase 6

        RDA2(16384, 4);
        stB(16384,2,t3); stA(16384,0,t3);
        BAR(); MFMA16(4); BAR();                    // phase 7

        RDA2(16384, 6);
        stB(16384,3,t3); stA(16384,2,t3);
        VMC6();
        BAR(); MFMA16(6); BAR();                    // phase 8
    }
    asm volatile("s_waitcnt vmcnt(0)" ::: "memory");  // one-time drain before exit

#undef RDB_ALL
#undef RDA2
#undef MFMA16
#undef BAR
#undef VMC6

    // ---- epilogue ----
    if constexpr (G1) {
        float bv[4];
        #pragma unroll
        for (int n = 0; n < 4; ++n)
            bv[n] = bias[e * DOUT + (nt << 8) + (wn << 6) + (n << 4) + l15];
        #pragma unroll
        for (int m = 0; m < 8; ++m) {
            #pragma unroll
            for (int rg = 0; rg < 4; ++rg) {
                const int trow = (mt << 8) + (wm << 7) + (m << 4) + (quad << 2) + rg;
                if (trow < cnt) {
                    ushort_t* yp = Yout + (size_t)(off + trow) * DOUT + (nt << 8) + (wn << 6);
                    #pragma unroll
                    for (int n = 0; n < 4; ++n)
                        yp[(n << 4) + l15] = f2bf(acc[m][n][rg] + bv[n]);
                }
            }
        }
    } else {
        float* pp = Pout + (size_t)kq * ((size_t)TTOK * SDIM);
        #pragma unroll
        for (int m = 0; m < 8; ++m) {
            #pragma unroll
            for (int rg = 0; rg < 4; ++rg) {
                const int trow = (mt << 8) + (wm << 7) + (m << 4) + (quad << 2) + rg;
                if (trow < cnt) {
                    float* op = pp + (size_t)(off + trow) * SDIM + (nt << 8) + (wn << 6);
                    #pragma unroll
                    for (int n = 0; n < 4; ++n)
                        op[(n << 4) + l15] = acc[m][n][rg];
                }
            }
        }
    }
}

__global__ __launch_bounds__(256)
void reduce4_kernel(const float* __restrict__ P, float* __restrict__ O) {
    const int i = blockIdx.x * 256 + threadIdx.x;   // float4 index
    const size_t S = (size_t)TTOK * SDIM;
    const float4 a = ((const float4*)P)[i];
    const float4 b = ((const float4*)(P + S))[i];
    const float4 c = ((const float4*)(P + 2 * S))[i];
    const float4 d = ((const float4*)(P + 3 * S))[i];
    ((float4*)O)[i] = make_float4(a.x + b.x + c.x + d.x, a.y + b.y + c.y + d.y,
                                  a.z + b.z + c.z + d.z, a.w + b.w + c.w + d.w);
}

// ================= fallback (R1, correct, ws >= 64 MiB) =================
__global__ __launch_bounds__(256, 2)
void gemm1_o(const float* __restrict__ X, const int* __restrict__ counts,
             const float* __restrict__ W, const float* __restrict__ bias,
             ushort_t* __restrict__ Y) {
    __shared__ __align__(16) ushort_t As[128 * LDSS];
    __shared__ __align__(16) ushort_t Bs[128 * LDSS];
    const int bid = blockIdx.x;
    const int e = bid >> 7, r_ = bid & 127;
    const int n_tile = r_ >> 2, m_tile = r_ & 3;
    int off = 0;
    for (int i = 0; i < e; ++i) off += counts[i];
    const int cnt = counts[e];
    const int t = threadIdx.x, wave = t >> 6, lane = t & 63;
    const int wm = (wave & 1) << 6, wn = (wave >> 1) << 6;
    const int l15 = lane & 15, quad = lane >> 4;
    const float* Wp = W + (size_t)e * DOUT * DIN + (size_t)(n_tile << 7) * DIN;
    floatx4 acc[4][4] = {};
    const int srow = t >> 3, scol = (t & 7) << 2;
    for (int k0 = 0; k0 < DIN; k0 += 32) {
        #pragma unroll
        for (int p = 0; p < 4; ++p) {
            const int row = srow + (p << 5);
            int grow = off + (m_tile << 7) + row;
            if (grow >= TTOK) grow = 0;
            const float4 v = *(const float4*)(X + (size_t)grow * DIN + k0 + scol);
            unsigned lo = (unsigned)f2bf(v.x) | ((unsigned)f2bf(v.y) << 16);
            unsigned hi = (unsigned)f2bf(v.z) | ((unsigned)f2bf(v.w) << 16);
            *(uint2*)&As[row * LDSS + scol] = make_uint2(lo, hi);
        }
        #pragma unroll
        for (int p = 0; p < 4; ++p) {
            const int row = srow + (p << 5);
            const float4 v = *(const float4*)(Wp + (size_t)row * DIN + k0 + scol);
            unsigned lo = (unsigned)f2bf(v.x) | ((unsigned)f2bf(v.y) << 16);
            unsigned hi = (unsigned)f2bf(v.z) | ((unsigned)f2bf(v.w) << 16);
            *(uint2*)&Bs[row * LDSS + scol] = make_uint2(lo, hi);
        }
        __syncthreads();
        short8 af[4], bfr[4];
        #pragma unroll
        for (int i = 0; i < 4; ++i) {
            af[i]  = *(const short8*)&As[(wm + (i << 4) + l15) * LDSS + (quad << 3)];
            bfr[i] = *(const short8*)&Bs[(wn + (i << 4) + l15) * LDSS + (quad << 3)];
        }
        #pragma unroll
        for (int mi = 0; mi < 4; ++mi)
            #pragma unroll
            for (int ni = 0; ni < 4; ++ni)
                acc[mi][ni] = __builtin_amdgcn_mfma_f32_16x16x32_bf16(
                    af[mi], bfr[ni], acc[mi][ni], 0, 0, 0);
        __syncthreads();
    }
    float bv[4];
    #pragma unroll
    for (int ni = 0; ni < 4; ++ni)
        bv[ni] = bias[e * DOUT + (n_tile << 7) + wn + (ni << 4) + l15];
    #pragma unroll
    for (int mi = 0; mi < 4; ++mi)
        #pragma unroll
        for (int rg = 0; rg < 4; ++rg) {
            const int trow = (m_tile << 7) + wm + (mi << 4) + (quad << 2) + rg;
            if (trow < cnt) {
                ushort_t* yp = Y + (size_t)(off + trow) * DOUT + (n_tile << 7) + wn;
                #pragma unroll
                for (int ni = 0; ni < 4; ++ni)
                    yp[(ni << 4) + l15] = f2bf(acc[mi][ni][rg] + bv[ni]);
            }
        }
}

__global__ __launch_bounds__(256, 2)
void gemm2_o(const ushort_t* __restrict__ Y, const int* __restrict__ counts,
             const float* __restrict__ C, float* __restrict__ O) {
    __shared__ __align__(16) ushort_t As[128 * LDSS];
    __shared__ __align__(16) ushort_t Bs[128 * LDSS];
    const int bid = blockIdx.x;
    const int e = bid >> 4, r_ = bid & 15;
    const int n_tile = r_ >> 2, m_tile = r_ & 3;
    int off = 0;
    for (int i = 0; i < e; ++i) off += counts[i];
    const int cnt = counts[e];
    const int t = threadIdx.x, wave = t >> 6, lane = t & 63;
    const int wm = (wave & 1) << 6, wn = (wave >> 1) << 6;
    const int l15 = lane & 15, quad = lane >> 4;
    const float* Cp = C + (size_t)e * SDIM * DOUT + (size_t)(n_tile << 7) * DOUT;
    floatx4 acc[4][4] = {};
    const int arow = t >> 2, achk = (t & 3) << 3;
    const int srow = t >> 3, scol = (t & 7) << 2;
    for (int k0 = 0; k0 < DOUT; k0 += 32) {
        #pragma unroll
        for (int p = 0; p < 2; ++p) {
            const int row = arow + (p << 6);
            int grow = off + (m_tile << 7) + row;
            if (grow >= TTOK) grow = 0;
            const short8 v = *(const short8*)(Y + (size_t)grow * DOUT + k0 + achk);
            *(short8*)&As[row * LDSS + achk] = v;
        }
        #pragma unroll
        for (int p = 0; p < 4; ++p) {
            const int row = srow + (p << 5);
            const float4 v = *(const float4*)(Cp + (size_t)row * DOUT + k0 + scol);
            unsigned lo = (unsigned)f2bf(v.x) | ((unsigned)f2bf(v.y) << 16);
            unsigned hi = (unsigned)f2bf(v.z) | ((unsigned)f2bf(v.w) << 16);
            *(uint2*)&Bs[row * LDSS + scol] = make_uint2(lo, hi);
        }
        __syncthreads();
        short8 af[4], bfr[4];
        #pragma unroll
        for (int i = 0; i < 4; ++i) {
            af[i]  = *(const short8*)&As[(wm + (i << 4) + l15) * LDSS + (quad << 3)];
            bfr[i] = *(const short8*)&Bs[(wn + (i << 4) + l15) * LDSS + (quad << 3)];
        }
        #pragma unroll
        for (int mi = 0; mi < 4; ++mi)
            #pragma unroll
            for (int ni = 0; ni < 4; ++ni)
                acc[mi][ni] = __builtin_amdgcn_mfma_f32_16x16x32_bf16(
                    af[mi], bfr[ni], acc[mi][ni], 0, 0, 0);
        __syncthreads();
    }
    #pragma unroll
    for (int mi = 0; mi < 4; ++mi)
        #pragma unroll
        for (int rg = 0; rg < 4; ++rg) {
            const int trow = (m_tile << 7) + wm + (mi << 4) + (quad << 2) + rg;
            if (trow < cnt) {
                float* op = O + (size_t)(off + trow) * SDIM + (n_tile << 7) + wn;
                #pragma unroll
                for (int ni = 0; ni < 4; ++ni)
                    op[(ni << 4) + l15] = acc[mi][ni][rg];
            }
        }
}

extern "C" void kernel_launch(void* const* d_in, const int* in_sizes, int n_in,
                              void* d_out, int out_size, void* d_ws, size_t ws_size,
                              hipStream_t stream) {
    const float* X      = (const float*)d_in[0];
    const int*   counts = (const int*)d_in[1];
    const float* W      = (const float*)d_in[2];
    const float* bias   = (const float*)d_in[3];
    const float* comp   = (const float*)d_in[4];
    float* out = (float*)d_out;

    const size_t OFF_XB = 0;
    const size_t OFF_WB = 16777216;     // 16 MiB
    const size_t OFF_CB = 150994944;    // 16+128 MiB
    const size_t OFF_Y  = 218103808;    // +64 MiB
    const size_t NEED   = 285212672;    // 272 MiB total

    if (ws_size >= NEED) {
        ushort_t* Xb = (ushort_t*)((char*)d_ws + OFF_XB);
        ushort_t* Wb = (ushort_t*)((char*)d_ws + OFF_WB);
        ushort_t* Cb = (ushort_t*)((char*)d_ws + OFF_CB);
        ushort_t* Y  = (ushort_t*)((char*)d_ws + OFF_Y);
        float*    P  = (float*)((char*)d_ws + OFF_WB);   // 64 MiB, overlays Wb (dead after gemm1)

        cvt_kernel<<<dim3(4096),  dim3(256), 0, stream>>>(X, Xb, 1048576);
        cvt_kernel<<<dim3(32768), dim3(256), 0, stream>>>(W, Wb, 8388608);
        cvt_kernel<<<dim3(16384), dim3(256), 0, stream>>>(comp, Cb, 4194304);
        gemm8p<true><<<dim3(512),  dim3(512), 0, stream>>>(Xb, counts, Wb, bias, Y, nullptr);
        gemm8p<false><<<dim3(256), dim3(512), 0, stream>>>(Y, counts, Cb, nullptr, nullptr, P);
        reduce4_kernel<<<dim3(4096), dim3(256), 0, stream>>>(P, out);
    } else {
        ushort_t* Y = (ushort_t*)d_ws;   // 64 MiB
        gemm1_o<<<dim3(2048), dim3(256), 0, stream>>>(X, counts, W, bias, Y);
        gemm2_o<<<dim3(256),  dim3(256), 0, stream>>>(Y, counts, comp, out);
    }
}

// Round 2
// 566.290 us; speedup vs baseline: 1.1560x; 1.1182x over previous
//
#include <hip/hip_runtime.h>

// FMoELinearProj — R4: drop W/comp cvt kernels. Both GEMMs are a single
// 256x256xBK=64 8-phase template: A (bf16) staged via global_load_lds with
// source-side granule swizzle; B read DIRECTLY as fp32, reg-staged 2 phases
// ahead, converted in-register (v_cvt_pk_bf16_f32) and ds_write_b128'd with
// write-side granule swizzle. Uniform counted vmcnt gates (6/4/8), raw
// s_barrier, setprio around MFMA. Saves ~384 MiB HBM vs R3.
// ws layout: Xb 16MiB @0, Y 64MiB @16Mi, P 64MiB @80Mi. NEED=160MiB.

#define NEXP 16
#define TTOK 8192
#define DIN  1024
#define DOUT 4096
#define SDIM 512
#define LDSS 40   // fallback-path LDS stride

typedef short short8 __attribute__((ext_vector_type(8)));
typedef float floatx4 __attribute__((ext_vector_type(4)));
typedef unsigned short ushort_t;

__device__ __forceinline__ ushort_t f2bf(float f) {
    union { float f; unsigned u; } v; v.f = f;
    unsigned r = v.u + 0x7FFFu + ((v.u >> 16) & 1u);   // RNE
    return (ushort_t)(r >> 16);
}

__device__ __forceinline__ unsigned cvtpk(float lo, float hi) {
    unsigned r;
    asm("v_cvt_pk_bf16_f32 %0, %1, %2" : "=v"(r) : "v"(lo), "v"(hi));
    return r;
}

#define GLL16(g, l) __builtin_amdgcn_global_load_lds( \
    (const __attribute__((address_space(1))) void*)(g), \
    (__attribute__((address_space(3))) void*)(l), 16, 0, 0)

// ---------------- fp32 -> bf16 streaming convert (X only) ----------------
__global__ __launch_bounds__(256)
void cvt_kernel(const float* __restrict__ src, ushort_t* __restrict__ dst, int n8) {
    const int i = blockIdx.x * 256 + threadIdx.x;
    if (i >= n8) return;
    const float4 a = ((const float4*)src)[2 * i];
    const float4 b = ((const float4*)src)[2 * i + 1];
    short8 o;
    o[0] = (short)f2bf(a.x); o[1] = (short)f2bf(a.y);
    o[2] = (short)f2bf(a.z); o[3] = (short)f2bf(a.w);
    o[4] = (short)f2bf(b.x); o[5] = (short)f2bf(b.y);
    o[6] = (short)f2bf(b.z); o[7] = (short)f2bf(b.w);
    ((short8*)dst)[i] = o;
}

// ============== 8-phase 256x256 GEMM, BK=64 (A bf16 GLL16, B fp32 reg-staged) =====
// 8 waves = 2(M) x 4(N); per-wave 128x64 out; acc[8][4]; LDS 2x(A 32K + B 32K).
// Per tile t: P1{rdB-all+rdA m01 | GLL16 A'(q0,q1) | vmcnt(6) | write B'(q0,q1)}
//             P2{rdA m23 | GLL16 A'(q2,q3) | vmcnt(4) | write B'(q2,q3)}
//             P3{rdA m45 | load B''(q0,q1)}  P4{rdA m67 | load B''(q2,q3) | vmcnt(8)}
// each phase: lgkmcnt(0) (publish ds_writes), barrier, setprio+16 MFMA, barrier.
// FIFO ledger (per tile: 2G,2G,4L,4L): gates drain exactly the quarters being
// consumed; 8-12 vmem ops always in flight, never drained to 0 in the loop.
template<bool G1>
__global__ __launch_bounds__(512, 2)
void gemm8p(const ushort_t* __restrict__ Ain, const int* __restrict__ counts,
            const float* __restrict__ Bf, const float* __restrict__ bias,
            ushort_t* __restrict__ Yout, float* __restrict__ Pout) {
    __shared__ __align__(16) ushort_t As[2 * 16384];
    __shared__ __align__(16) ushort_t Bs[2 * 16384];

    int e, mt, nt, kq;
    if constexpr (G1) {
        // 512 blocks -> 8 XCDs x 64 slots (2 experts/XCD); m fastest (W-tile share)
        const int l = ((blockIdx.x & 7) << 6) | (blockIdx.x >> 3);
        e = l >> 5; nt = (l >> 1) & 15; mt = l & 1; kq = 0;
    } else {
        // 256 blocks -> 8 XCDs x 32 slots; m fastest, split-K=4
        const int l = ((blockIdx.x & 7) << 5) | (blockIdx.x >> 3);
        e = l >> 4; kq = (l >> 2) & 3; nt = (l >> 1) & 1; mt = l & 1;
    }
    const int LDK = G1 ? DIN : DOUT;   // k-stride for both A (bf16) and B (fp32)

    int off = 0;
    for (int i = 0; i < e; ++i) off += counts[i];
    const int cnt = counts[e];

    const int tid = threadIdx.x, wave = tid >> 6, lane = tid & 63;
    const int wm = wave >> 2, wn = wave & 3;
    const int l15 = lane & 15, quad = lane >> 4;
    const int srow = (wave << 3) + (lane >> 3);            // row within a 64-row quarter
    const int swz8 = ((lane & 7) ^ (lane >> 3)) << 3;      // granule swizzle (elems)
    const int aseg = off + (mt << 8);

    // A row base pointers (bf16, source-side swizzle so linear GLL16 dest works)
    const ushort_t* ap[4];
    #pragma unroll
    for (int q = 0; q < 4; ++q) {
        int r = aseg + (q << 6) + srow; if (r >= TTOK) r = TTOK - 1;
        ap[q] = Ain + (size_t)r * LDK + (G1 ? 0 : (kq << 10)) + swz8;
    }
    // B row base pointers (fp32, linear source; swizzle applied on ds_write)
    const float* bpq[4];
    {
        const float* Bbase = G1
            ? (Bf + (size_t)e * DOUT * DIN  + ((size_t)(nt << 8)) * DIN)
            : (Bf + (size_t)e * SDIM * DOUT + ((size_t)(nt << 8)) * DOUT + (kq << 10));
        #pragma unroll
        for (int q = 0; q < 4; ++q)
            bpq[q] = Bbase + (size_t)((q << 6) + srow) * LDK + ((lane & 7) << 3);
    }
    const int aLdsW  = (wave << 9);             // + (q<<12) + buf
    const int bWrOff = (srow << 6) + swz8;      // + (q<<12) + buf

    auto rdA = [&](int bufe, int m, int s) -> short8 {
        return *(const short8*)&As[bufe + ((wm << 7) + (m << 4) + l15) * 64
                                   + ((((s << 2) | quad) ^ (lane & 7)) << 3)];
    };
    auto rdB = [&](int bufe, int n, int s) -> short8 {
        return *(const short8*)&Bs[bufe + ((wn << 6) + (n << 4) + l15) * 64
                                   + ((((s << 2) | quad) ^ (lane & 7)) << 3)];
    };

    floatx4 acc[8][4] = {};
    short8 bfv[4][2], af0[2], af1[2];
    float4 bq[4][2];

#define GA(NB, q, kt) GLL16(ap[q] + ((kt) << 6), As + (NB) + ((q) << 12) + aLdsW)
#define LB(q, kt) { const float* _p = bpq[q] + ((kt) << 6); \
    bq[q][0] = *(const float4*)_p; bq[q][1] = *(const float4*)(_p + 4); }
#define WRB(NB, q) { uint4 _w; \
    _w.x = cvtpk(bq[q][0].x, bq[q][0].y); _w.y = cvtpk(bq[q][0].z, bq[q][0].w); \
    _w.z = cvtpk(bq[q][1].x, bq[q][1].y); _w.w = cvtpk(bq[q][1].z, bq[q][1].w); \
    *(uint4*)&Bs[(NB) + ((q) << 12) + bWrOff] = _w; }
#define RDB_ALL(BUFE) { _Pragma("unroll") \
    for (int n = 0; n < 4; ++n) { bfv[n][0] = rdB(BUFE,n,0); bfv[n][1] = rdB(BUFE,n,1); } }
#define RDA2(BUFE, M0) { af0[0]=rdA(BUFE,M0,0); af0[1]=rdA(BUFE,M0,1); \
                         af1[0]=rdA(BUFE,(M0)+1,0); af1[1]=rdA(BUFE,(M0)+1,1); }
#define MFMA16(M0) { \
    __builtin_amdgcn_s_setprio(1); \
    _Pragma("unroll") for (int n = 0; n < 4; ++n) { \
      acc[M0][n]     = __builtin_amdgcn_mfma_f32_16x16x32_bf16(af0[0], bfv[n][0], acc[M0][n],     0,0,0); \
      acc[M0][n]     = __builtin_amdgcn_mfma_f32_16x16x32_bf16(af0[1], bfv[n][1], acc[M0][n],     0,0,0); \
      acc[(M0)+1][n] = __builtin_amdgcn_mfma_f32_16x16x32_bf16(af1[0], bfv[n][0], acc[(M0)+1][n], 0,0,0); \
      acc[(M0)+1][n] = __builtin_amdgcn_mfma_f32_16x16x32_bf16(af1[1], bfv[n][1], acc[(M0)+1][n], 0,0,0); } \
    __builtin_amdgcn_s_setprio(0); }
#define VMC(N) asm volatile("s_waitcnt vmcnt(" #N ")" ::: "memory")
#define LGKM0  asm volatile("s_waitcnt lgkmcnt(0)" ::: "memory")
#define BAR()  __builtin_amdgcn_s_barrier()

#define TILE(BUF, NBUF, KA, KB) { \
    RDB_ALL(BUF); RDA2(BUF, 0); \
    GA(NBUF, 0, KA); GA(NBUF, 1, KA); \
    VMC(6); WRB(NBUF, 0); WRB(NBUF, 1); \
    LGKM0; BAR(); MFMA16(0); BAR(); \
    RDA2(BUF, 2); \
    GA(NBUF, 2, KA); GA(NBUF, 3, KA); \
    VMC(4); WRB(NBUF, 2); WRB(NBUF, 3); \
    LGKM0; BAR(); MFMA16(2); BAR(); \
    RDA2(BUF, 4); \
    LB(0, KB); LB(1, KB); \
    BAR(); MFMA16(4); BAR(); \
    RDA2(BUF, 6); \
    LB(2, KB); LB(3, KB); \
    VMC(8); \
    BAR(); MFMA16(6); BAR(); }

    // ---- prologue: B(0) load+write, A(0) GLL16, B(1) load; prime FIFO = 8 ----
    LB(0, 0); LB(1, 0); LB(2, 0); LB(3, 0);
    GA(0, 0, 0); GA(0, 1, 0); GA(0, 2, 0); GA(0, 3, 0);
    VMC(4);
    WRB(0, 0); WRB(0, 1); WRB(0, 2); WRB(0, 3);
    LB(0, 1); LB(1, 1); LB(2, 1); LB(3, 1);
    VMC(8);
    LGKM0; BAR();

    #pragma unroll 1
    for (int it = 0; it < 8; ++it) {
        const int ka0 = 2 * it + 1;
        const int kb0 = (it < 7) ? 2 * it + 2 : 15;   // clamped dummies keep counts uniform
        const int kb1 = (it < 7) ? 2 * it + 3 : 15;
        TILE(0, 16384, ka0, kb0);       // tile 2it   (buf0): stage A(2it+1), load B(2it+2)
        TILE(16384, 0, kb0, kb1);       // tile 2it+1 (buf1): stage A(2it+2), load B(2it+3)
    }

#undef TILE
#undef GA
#undef LB
#undef WRB
#undef RDB_ALL
#undef RDA2
#undef MFMA16
#undef VMC
#undef LGKM0
#undef BAR

    // ---- epilogue ----
    if constexpr (G1) {
        float bv[4];
        #pragma unroll
        for (int n = 0; n < 4; ++n)
            bv[n] = bias[e * DOUT + (nt << 8) + (wn << 6) + (n << 4) + l15];
        #pragma unroll
        for (int m = 0; m < 8; ++m) {
            #pragma unroll
            for (int rg = 0; rg < 4; ++rg) {
                const int trow = (mt << 8) + (wm << 7) + (m << 4) + (quad << 2) + rg;
                if (trow < cnt) {
                    ushort_t* yp = Yout + (size_t)(off + trow) * DOUT + (nt << 8) + (wn << 6);
                    #pragma unroll
                    for (int n = 0; n < 4; ++n)
                        yp[(n << 4) + l15] = f2bf(acc[m][n][rg] + bv[n]);
                }
            }
        }
    } else {
        float* pp = Pout + (size_t)kq * ((size_t)TTOK * SDIM);
        #pragma unroll
        for (int m = 0; m < 8; ++m) {
            #pragma unroll
            for (int rg = 0; rg < 4; ++rg) {
                const int trow = (mt << 8) + (wm << 7) + (m << 4) + (quad << 2) + rg;
                if (trow < cnt) {
                    float* op = pp + (size_t)(off + trow) * SDIM + (nt << 8) + (wn << 6);
                    #pragma unroll
                    for (int n = 0; n < 4; ++n)
                        op[(n << 4) + l15] = acc[m][n][rg];
                }
            }
        }
    }
}

__global__ __launch_bounds__(256)
void reduce4_kernel(const float* __restrict__ P, float* __restrict__ O) {
    const int i = blockIdx.x * 256 + threadIdx.x;   // float4 index
    const size_t S = (size_t)TTOK * SDIM;
    const float4 a = ((const float4*)P)[i];
    const float4 b = ((const float4*)(P + S))[i];
    const float4 c = ((const float4*)(P + 2 * S))[i];
    const float4 d = ((const float4*)(P + 3 * S))[i];
    ((float4*)O)[i] = make_float4(a.x + b.x + c.x + d.x, a.y + b.y + c.y + d.y,
                                  a.z + b.z + c.z + d.z, a.w + b.w + c.w + d.w);
}

// ================= fallback (R1, correct, ws >= 64 MiB) =================
__global__ __launch_bounds__(256, 2)
void gemm1_o(const float* __restrict__ X, const int* __restrict__ counts,
             const float* __restrict__ W, const float* __restrict__ bias,
             ushort_t* __restrict__ Y) {
    __shared__ __align__(16) ushort_t As[128 * LDSS];
    __shared__ __align__(16) ushort_t Bs[128 * LDSS];
    const int bid = blockIdx.x;
    const int e = bid >> 7, r_ = bid & 127;
    const int n_tile = r_ >> 2, m_tile = r_ & 3;
    int off = 0;
    for (int i = 0; i < e; ++i) off += counts[i];
    const int cnt = counts[e];
    const int t = threadIdx.x, wave = t >> 6, lane = t & 63;
    const int wm = (wave & 1) << 6, wn = (wave >> 1) << 6;
    const int l15 = lane & 15, quad = lane >> 4;
    const float* Wp = W + (size_t)e * DOUT * DIN + (size_t)(n_tile << 7) * DIN;
    floatx4 acc[4][4] = {};
    const int srow = t >> 3, scol = (t & 7) << 2;
    for (int k0 = 0; k0 < DIN; k0 += 32) {
        #pragma unroll
        for (int p = 0; p < 4; ++p) {
            const int row = srow + (p << 5);
            int grow = off + (m_tile << 7) + row;
            if (grow >= TTOK) grow = 0;
            const float4 v = *(const float4*)(X + (size_t)grow * DIN + k0 + scol);
            unsigned lo = (unsigned)f2bf(v.x) | ((unsigned)f2bf(v.y) << 16);
            unsigned hi = (unsigned)f2bf(v.z) | ((unsigned)f2bf(v.w) << 16);
            *(uint2*)&As[row * LDSS + scol] = make_uint2(lo, hi);
        }
        #pragma unroll
        for (int p = 0; p < 4; ++p) {
            const int row = srow + (p << 5);
            const float4 v = *(const float4*)(Wp + (size_t)row * DIN + k0 + scol);
            unsigned lo = (unsigned)f2bf(v.x) | ((unsigned)f2bf(v.y) << 16);
            unsigned hi = (unsigned)f2bf(v.z) | ((unsigned)f2bf(v.w) << 16);
            *(uint2*)&Bs[row * LDSS + scol] = make_uint2(lo, hi);
        }
        __syncthreads();
        short8 af[4], bfr[4];
        #pragma unroll
        for (int i = 0; i < 4; ++i) {
            af[i]  = *(const short8*)&As[(wm + (i << 4) + l15) * LDSS + (quad << 3)];
            bfr[i] = *(const short8*)&Bs[(wn + (i << 4) + l15) * LDSS + (quad << 3)];
        }
        #pragma unroll
        for (int mi = 0; mi < 4; ++mi)
            #pragma unroll
            for (int ni = 0; ni < 4; ++ni)
                acc[mi][ni] = __builtin_amdgcn_mfma_f32_16x16x32_bf16(
                    af[mi], bfr[ni], acc[mi][ni], 0, 0, 0);
        __syncthreads();
    }
    float bv[4];
    #pragma unroll
    for (int ni = 0; ni < 4; ++ni)
        bv[ni] = bias[e * DOUT + (n_tile << 7) + wn + (ni << 4) + l15];
    #pragma unroll
    for (int mi = 0; mi < 4; ++mi)
        #pragma unroll
        for (int rg = 0; rg < 4; ++rg) {
            const int trow = (m_tile << 7) + wm + (mi << 4) + (quad << 2) + rg;
            if (trow < cnt) {
                ushort_t* yp = Y + (size_t)(off + trow) * DOUT + (n_tile << 7) + wn;
                #pragma unroll
                for (int ni = 0; ni < 4; ++ni)
                    yp[(ni << 4) + l15] = f2bf(acc[mi][ni][rg] + bv[ni]);
            }
        }
}

__global__ __launch_bounds__(256, 2)
void gemm2_o(const ushort_t* __restrict__ Y, const int* __restrict__ counts,
             const float* __restrict__ C, float* __restrict__ O) {
    __shared__ __align__(16) ushort_t As[128 * LDSS];
    __shared__ __align__(16) ushort_t Bs[128 * LDSS];
    const int bid = blockIdx.x;
    const int e = bid >> 4, r_ = bid & 15;
    const int n_tile = r_ >> 2, m_tile = r_ & 3;
    int off = 0;
    for (int i = 0; i < e; ++i) off += counts[i];
    const int cnt = counts[e];
    const int t = threadIdx.x, wave = t >> 6, lane = t & 63;
    const int wm = (wave & 1) << 6, wn = (wave >> 1) << 6;
    const int l15 = lane & 15, quad = lane >> 4;
    const float* Cp = C + (size_t)e * SDIM * DOUT + (size_t)(n_tile << 7) * DOUT;
    floatx4 acc[4][4] = {};
    const int arow = t >> 2, achk = (t & 3) << 3;
    const int srow = t >> 3, scol = (t & 7) << 2;
    for (int k0 = 0; k0 < DOUT; k0 += 32) {
        #pragma unroll
        for (int p = 0; p < 2; ++p) {
            const int row = arow + (p << 6);
            int grow = off + (m_tile << 7) + row;
            if (grow >= TTOK) grow = 0;
            const short8 v = *(const short8*)(Y + (size_t)grow * DOUT + k0 + achk);
            *(short8*)&As[row * LDSS + achk] = v;
        }
        #pragma unroll
        for (int p = 0; p < 4; ++p) {
            const int row = srow + (p << 5);
            const float4 v = *(const float4*)(Cp + (size_t)row * DOUT + k0 + scol);
            unsigned lo = (unsigned)f2bf(v.x) | ((unsigned)f2bf(v.y) << 16);
            unsigned hi = (unsigned)f2bf(v.z) | ((unsigned)f2bf(v.w) << 16);
            *(uint2*)&Bs[row * LDSS + scol] = make_uint2(lo, hi);
        }
        __syncthreads();
        short8 af[4], bfr[4];
        #pragma unroll
        for (int i = 0; i < 4; ++i) {
            af[i]  = *(const short8*)&As[(wm + (i << 4) + l15) * LDSS + (quad << 3)];
            bfr[i] = *(const short8*)&Bs[(wn + (i << 4) + l15) * LDSS + (quad << 3)];
        }
        #pragma unroll
        for (int mi = 0; mi < 4; ++mi)
            #pragma unroll
            for (int ni = 0; ni < 4; ++ni)
                acc[mi][ni] = __builtin_amdgcn_mfma_f32_16x16x32_bf16(
                    af[mi], bfr[ni], acc[mi][ni], 0, 0, 0);
        __syncthreads();
    }
    #pragma unroll
    for (int mi = 0; mi < 4; ++mi)
        #pragma unroll
        for (int rg = 0; rg < 4; ++rg) {
            const int trow = (m_tile << 7) + wm + (mi << 4) + (quad << 2) + rg;
            if (trow < cnt) {
                float* op = O + (size_t)(off + trow) * SDIM + (n_tile << 7) + wn;
                #pragma unroll
                for (int ni = 0; ni < 4; ++ni)
                    op[(ni << 4) + l15] = acc[mi][ni][rg];
            }
        }
}

extern "C" void kernel_launch(void* const* d_in, const int* in_sizes, int n_in,
                              void* d_out, int out_size, void* d_ws, size_t ws_size,
                              hipStream_t stream) {
    const float* X      = (const float*)d_in[0];
    const int*   counts = (const int*)d_in[1];
    const float* W      = (const float*)d_in[2];
    const float* bias   = (const float*)d_in[3];
    const float* comp   = (const float*)d_in[4];
    float* out = (float*)d_out;

    const size_t OFF_XB = 0;            // 16 MiB bf16 X
    const size_t OFF_Y  = 16777216;     // 64 MiB bf16 Y
    const size_t OFF_P  = 83886080;     // 64 MiB fp32 P (split-K partials)
    const size_t NEED   = 150994944;    // 144 MiB total

    if (ws_size >= NEED) {
        ushort_t* Xb = (ushort_t*)((char*)d_ws + OFF_XB);
        ushort_t* Y  = (ushort_t*)((char*)d_ws + OFF_Y);
        float*    P  = (float*)((char*)d_ws + OFF_P);

        cvt_kernel<<<dim3(4096), dim3(256), 0, stream>>>(X, Xb, 1048576);
        gemm8p<true><<<dim3(512),  dim3(512), 0, stream>>>(Xb, counts, W, bias, Y, nullptr);
        gemm8p<false><<<dim3(256), dim3(512), 0, stream>>>(Y, counts, comp, nullptr, nullptr, P);
        reduce4_kernel<<<dim3(4096), dim3(256), 0, stream>>>(P, out);
    } else {
        ushort_t* Y = (ushort_t*)d_ws;   // 64 MiB
        gemm1_o<<<dim3(2048), dim3(256), 0, stream>>>(X, counts, W, bias, Y);
        gemm2_o<<<dim3(256),  dim3(256), 0, stream>>>(Y, counts, comp, out);
    }
}